// Round 2
// baseline (220.729 us; speedup 1.0000x reference)
//
#include <hip/hip_runtime.h>
#include <stdint.h>

// RT-DETR post-processing, round 2: same exact selection semantics as the
// passing round-1 kernel (composite key (score_bits<<32)|~idx; score bits
// order == score order since scores in (0,1)), restructured for occupancy:
//   k1 hist    (128*8 blocks x 512): LDS histogram -> global per-row hist
//   k2 thresh  (128 x 64):           suffix-scan -> threshold bin T, count A
//   k3 collect (128*8 blocks x 512): gather candidates (bin >= T) to ws
//   k4 rank    (128 x 256):          exact O(M^2) rank + emit
// Assumption (holds for this data: M ~ 600): candidates per row <= CAP.

#define BATCH 128
#define NCLS 80
#define NQ 2000
#define ROW (NQ * NCLS)     // 160000
#define TOPK 300
#define NBINS 4096          // bin = score_bits >> 18
#define SPLIT 8
#define CHUNK (ROW / SPLIT) // 20000
#define CAP 2048

// ws layout (bytes):
//   cand : [BATCH][CAP] u64   @ 0          (2 MB)
//   hist : [BATCH][NBINS] u32 @ 2097152    (2 MB)   } zeroed each call
//   cnt  : [BATCH] u32        @ 4194304    (512 B)  }
//   ta   : [BATCH][2] u32     @ 4194816    (1 KB)
#define WS_CAND 0
#define WS_HIST (BATCH * CAP * 8)
#define WS_CNT  (WS_HIST + BATCH * NBINS * 4)
#define WS_TA   (WS_CNT + BATCH * 4)

__device__ __forceinline__ uint32_t score_bits(float x) {
  float e = expf(-fabsf(x));
  float num = (x >= 0.f) ? 1.f : e;
  float s = num / (1.f + e);
  return __float_as_uint(s);
}

__global__ __launch_bounds__(512)
void k1_hist(const float* __restrict__ logits, uint32_t* __restrict__ hist_g)
{
  __shared__ uint32_t h[NBINS];
  const int row = blockIdx.x >> 3;
  const int part = blockIdx.x & 7;
  const int tid = threadIdx.x;

  for (int i = tid; i < NBINS; i += 512) h[i] = 0;
  __syncthreads();

  const float4* p = (const float4*)(logits + (size_t)row * ROW + part * CHUNK);
  for (int i = tid; i < CHUNK / 4; i += 512) {
    float4 v = p[i];
    #pragma unroll
    for (int c = 0; c < 4; ++c) {
      uint32_t bk = score_bits((&v.x)[c]) >> 18;
      bk = bk < NBINS ? bk : NBINS - 1;
      atomicAdd(&h[bk], 1u);
    }
  }
  __syncthreads();

  uint32_t* hrow = hist_g + (size_t)row * NBINS;
  for (int i = tid; i < NBINS; i += 512) {
    uint32_t v = h[i];
    if (v) atomicAdd(&hrow[i], v);
  }
}

__global__ void k2_thresh(const uint32_t* __restrict__ hist_g,
                          uint32_t* __restrict__ ta_g)
{
  const int row = blockIdx.x;
  const int lane = threadIdx.x;   // 64 threads = 1 wave
  const uint32_t* h = hist_g + (size_t)row * NBINS;

  // level 1: 64 superchunks of 64 bins
  uint32_t s = 0;
  for (int j = 0; j < 64; ++j) s += h[lane * 64 + j];
  uint32_t suf = s;
  #pragma unroll
  for (int d = 1; d < 64; d <<= 1) {
    uint32_t o = __shfl_down(suf, d, 64);
    if (lane + d < 64) suf += o;
  }
  unsigned long long m = __ballot(suf >= (uint32_t)TOPK);
  int sc = 63 - __builtin_clzll(m);
  uint32_t acc0 = (sc < 63) ? __shfl(suf, sc + 1, 64) : 0u;
  acc0 = __shfl(acc0, 0, 64); // make wave-uniform copy path safe
  // recompute acc0 properly on all lanes: broadcast from lane 0 not needed;
  // each lane computed same sc, and __shfl already gives uniform value.

  // level 2: 64 bins inside superchunk sc
  uint32_t hv = h[sc * 64 + lane];
  uint32_t suf2 = hv;
  #pragma unroll
  for (int d = 1; d < 64; d <<= 1) {
    uint32_t o = __shfl_down(suf2, d, 64);
    if (lane + d < 64) suf2 += o;
  }
  m = __ballot((acc0 + suf2) >= (uint32_t)TOPK);
  int bk = 63 - __builtin_clzll(m);
  uint32_t A = acc0 + ((bk < 63) ? __shfl(suf2, bk + 1, 64) : 0u);
  if (lane == 0) {
    ta_g[row * 2] = (uint32_t)(sc * 64 + bk);
    ta_g[row * 2 + 1] = A;
  }
}

__global__ __launch_bounds__(512)
void k3_collect(const float* __restrict__ logits,
                const uint32_t* __restrict__ ta_g,
                uint64_t* __restrict__ cand_g,
                uint32_t* __restrict__ cnt_g)
{
  const int row = blockIdx.x >> 3;
  const int part = blockIdx.x & 7;
  const int tid = threadIdx.x;
  const uint32_t T = ta_g[row * 2];

  const float4* p = (const float4*)(logits + (size_t)row * ROW + part * CHUNK);
  uint64_t* crow = cand_g + (size_t)row * CAP;
  for (int i = tid; i < CHUNK / 4; i += 512) {
    float4 v = p[i];
    #pragma unroll
    for (int c = 0; c < 4; ++c) {
      uint32_t bits = score_bits((&v.x)[c]);
      uint32_t bk = bits >> 18;
      bk = bk < NBINS ? bk : NBINS - 1;
      if (bk >= T) {
        uint32_t pos = atomicAdd(&cnt_g[row], 1u);
        uint32_t idx = (uint32_t)(part * CHUNK + i * 4 + c);
        if (pos < CAP) crow[pos] = ((uint64_t)bits << 32) | (uint32_t)~idx;
      }
    }
  }
}

__global__ __launch_bounds__(256)
void k4_rank(const uint64_t* __restrict__ cand_g,
             const uint32_t* __restrict__ cnt_g,
             const float* __restrict__ boxes,
             const int* __restrict__ sizes,
             float* __restrict__ out)
{
  __shared__ uint64_t cand[CAP];  // 16 KB
  const int b = blockIdx.x;
  const int tid = threadIdx.x;
  const uint32_t M = cnt_g[b] < CAP ? cnt_g[b] : CAP;

  const uint64_t* crow = cand_g + (size_t)b * CAP;
  for (int i = tid; i < (int)M; i += 256) cand[i] = crow[i];
  __syncthreads();

  float* out_labels = out;
  float4* out_boxes = (float4*)(out + BATCH * TOPK);
  float* out_scores = out + BATCH * TOPK + BATCH * TOPK * 4;
  const float4* brow = (const float4*)(boxes + (size_t)b * NQ * 4);
  const float img_h = (float)sizes[2 * b];
  const float img_w = (float)sizes[2 * b + 1];

  for (int i = tid; i < (int)M; i += 256) {
    uint64_t key = cand[i];
    int rank = 0;
    for (uint32_t mi = 0; mi < M; ++mi) rank += (cand[mi] > key) ? 1 : 0;
    if (rank < TOPK) {
      uint32_t bits = (uint32_t)(key >> 32);
      uint32_t idx = ~(uint32_t)(key & 0xFFFFFFFFull);
      int q = (int)(idx / NCLS);
      int cls = (int)idx - q * NCLS;
      float4 pb = brow[q];
      float x0 = (pb.x - 0.5f * pb.z) * img_w;
      float y0 = (pb.y - 0.5f * pb.w) * img_h;
      float w2 = pb.z * img_w;
      float h2 = pb.w * img_h;
      x0 = fmaxf(x0, 0.f); y0 = fmaxf(y0, 0.f);
      w2 = fmaxf(w2, 1.f); h2 = fmaxf(h2, 1.f);
      int o = b * TOPK + rank;
      out_labels[o] = (float)cls;
      out_boxes[o] = make_float4(x0, y0, w2, h2);
      out_scores[o] = __uint_as_float(bits);
    }
  }
}

extern "C" void kernel_launch(void* const* d_in, const int* in_sizes, int n_in,
                              void* d_out, int out_size, void* d_ws, size_t ws_size,
                              hipStream_t stream) {
  const float* logits = (const float*)d_in[0];
  const float* boxes  = (const float*)d_in[1];
  const int*   sizes  = (const int*)d_in[2];
  float*       outp   = (float*)d_out;
  (void)in_sizes; (void)n_in; (void)out_size; (void)ws_size;

  char* ws = (char*)d_ws;
  uint64_t* cand_g = (uint64_t*)(ws + WS_CAND);
  uint32_t* hist_g = (uint32_t*)(ws + WS_HIST);
  uint32_t* cnt_g  = (uint32_t*)(ws + WS_CNT);
  uint32_t* ta_g   = (uint32_t*)(ws + WS_TA);

  // zero hist + cnt (contiguous region)
  hipMemsetAsync(ws + WS_HIST, 0, BATCH * NBINS * 4 + BATCH * 4, stream);

  k1_hist<<<BATCH * SPLIT, 512, 0, stream>>>(logits, hist_g);
  k2_thresh<<<BATCH, 64, 0, stream>>>(hist_g, ta_g);
  k3_collect<<<BATCH * SPLIT, 512, 0, stream>>>(logits, ta_g, cand_g, cnt_g);
  k4_rank<<<BATCH, 256, 0, stream>>>(cand_g, cnt_g, boxes, sizes, outp);
}

// Round 3
// 50.909 us; speedup vs baseline: 4.3358x; 4.3358x over previous
//
#include <hip/hip_runtime.h>
#include <stdint.h>

// RT-DETR post-processing, round 3.
// Selection semantics identical to the passing R1 kernel: top-300 by
// composite key (sigmoid_bits<<32)|~idx  (score in (0,1) => positive float
// => bit order == value order; ~idx gives lower-index-first on ties).
//
// Fast path: candidates gated on RAW logit > 2.6 (monotone in score).
// For N(0,1) logits: ~745 candidates/row (±5sigma in [610,880]), so
// >=TOPK and <=CAP hold with astronomical margin. A per-row flag + exact
// fallback kernel (R1's proven algorithm) covers any other input.
//
// R2 lesson applied: per-row atomic counters padded to 128B lines (R2's
// 154us k3 was atomic serialization on 2 shared cache lines).

#define BATCH 128
#define NCLS 80
#define NQ 2000
#define ROW (NQ * NCLS)     // 160000
#define TOPK 300
#define CAP 1536
#define LOGIT_T 2.6f
#define SPLIT 16
#define CHUNK (ROW / SPLIT) // 10000

// ws layout (bytes):
//   cand : [BATCH][CAP] u64 @ 0        (1.5 MB)
//   cnt  : [BATCH][32] u32  @ WS_CNT   (16 KB, 128B stride)  } zeroed
//   flag : [BATCH] u32      @ WS_FLAG  (512 B)               } each call
#define WS_CAND 0
#define WS_CNT  (BATCH * CAP * 8)
#define WS_FLAG (WS_CNT + BATCH * 32 * 4)

__device__ __forceinline__ uint32_t score_bits(float x) {
  float e = expf(-fabsf(x));
  float num = (x >= 0.f) ? 1.f : e;
  float s = num / (1.f + e);
  return __float_as_uint(s);
}

// ---- k1: stream logits, collect candidates over fixed logit threshold ----
__global__ __launch_bounds__(256)
void k1_collect(const float* __restrict__ logits,
                uint64_t* __restrict__ cand_g,
                uint32_t* __restrict__ cnt_g)
{
  const int row = blockIdx.x >> 4;          // SPLIT=16
  const int part = blockIdx.x & 15;
  const int tid = threadIdx.x;

  const float4* p = (const float4*)(logits + (size_t)row * ROW + part * CHUNK);
  uint64_t* crow = cand_g + (size_t)row * CAP;
  uint32_t* cnt = cnt_g + row * 32;         // 128B-padded counter

  for (int i = tid; i < CHUNK / 4; i += 256) {
    float4 v = p[i];
    #pragma unroll
    for (int c = 0; c < 4; ++c) {
      float x = (&v.x)[c];
      if (x > LOGIT_T) {
        uint32_t bits = score_bits(x);
        uint32_t idx = (uint32_t)(part * CHUNK + i * 4 + c);
        uint32_t pos = atomicAdd(cnt, 1u);
        if (pos < CAP) crow[pos] = ((uint64_t)bits << 32) | (uint32_t)~idx;
      }
    }
  }
}

// ---- k2: exact O(M^2) rank on candidates, emit; flag rows needing fallback ----
__global__ __launch_bounds__(1024)
void k2_rank(const uint64_t* __restrict__ cand_g,
             const uint32_t* __restrict__ cnt_g,
             uint32_t* __restrict__ flag_g,
             const float* __restrict__ boxes,
             const int* __restrict__ sizes,
             float* __restrict__ out)
{
  __shared__ uint64_t cand[CAP];  // 12 KB
  const int b = blockIdx.x;
  const int tid = threadIdx.x;
  const uint32_t cnt = cnt_g[b * 32];

  if (cnt < TOPK || cnt > CAP) {          // threshold assumption failed
    if (tid == 0) flag_g[b] = 1u;
    return;
  }
  const uint32_t M = cnt;

  const uint64_t* crow = cand_g + (size_t)b * CAP;
  for (int i = tid; i < (int)M; i += 1024) cand[i] = crow[i];
  __syncthreads();

  float* out_labels = out;
  float4* out_boxes = (float4*)(out + BATCH * TOPK);
  float* out_scores = out + BATCH * TOPK + BATCH * TOPK * 4;
  const float4* brow = (const float4*)(boxes + (size_t)b * NQ * 4);
  const float img_h = (float)sizes[2 * b];
  const float img_w = (float)sizes[2 * b + 1];

  for (int i = tid; i < (int)M; i += 1024) {
    uint64_t key = cand[i];
    int rank = 0;
    for (uint32_t mi = 0; mi < M; ++mi) rank += (cand[mi] > key) ? 1 : 0;
    if (rank < TOPK) {
      uint32_t bits = (uint32_t)(key >> 32);
      uint32_t idx = ~(uint32_t)(key & 0xFFFFFFFFull);
      int q = (int)(idx / NCLS);
      int cls = (int)idx - q * NCLS;
      float4 pb = brow[q];
      float x0 = (pb.x - 0.5f * pb.z) * img_w;
      float y0 = (pb.y - 0.5f * pb.w) * img_h;
      float w2 = pb.z * img_w;
      float h2 = pb.w * img_h;
      x0 = fmaxf(x0, 0.f); y0 = fmaxf(y0, 0.f);
      w2 = fmaxf(w2, 1.f); h2 = fmaxf(h2, 1.f);
      int o = b * TOPK + rank;
      out_labels[o] = (float)cls;
      out_boxes[o] = make_float4(x0, y0, w2, h2);
      out_scores[o] = __uint_as_float(bits);
    }
  }
}

// ---- k3: exact per-row fallback (R1's proven kernel), runs only if flagged ----
#define NB 8192
#define FCAP 2048

__global__ __launch_bounds__(1024, 1)
void k3_fallback(const uint32_t* __restrict__ flag_g,
                 const float* __restrict__ logits,
                 const float* __restrict__ boxes,
                 const int* __restrict__ sizes,
                 float* __restrict__ out)
{
  const int b = blockIdx.x;
  if (!flag_g[b]) return;   // uniform across block, before any barrier

  __shared__ uint32_t hist[NB];
  __shared__ uint64_t cand[FCAP];
  __shared__ uint32_t csum[1024];
  __shared__ uint32_t hist2[256];
  __shared__ uint32_t sh_T, sh_A, sh_T2, sh_cnt;

  const int tid = threadIdx.x;
  const float4* row4 = (const float4*)(logits + (size_t)b * ROW);

  for (int i = tid; i < NB; i += 1024) hist[i] = 0;
  if (tid == 0) sh_cnt = 0;
  __syncthreads();

  for (int i = tid; i < ROW / 4; i += 1024) {
    float4 v = row4[i];
    #pragma unroll
    for (int c = 0; c < 4; ++c) {
      uint32_t bk = score_bits((&v.x)[c]) >> 17;
      bk = bk < NB ? bk : NB - 1;
      atomicAdd(&hist[bk], 1u);
    }
  }
  __syncthreads();

  {
    uint32_t s = 0;
    #pragma unroll
    for (int j = 0; j < NB / 1024; ++j) s += hist[tid * (NB / 1024) + j];
    csum[tid] = s;
  }
  __syncthreads();

  if (tid < 64) {
    const int lane = tid;
    uint32_t ss = 0;
    if (lane < 32) {
      #pragma unroll
      for (int j = 0; j < 32; ++j) ss += csum[lane * 32 + j];
    }
    uint32_t suf = ss;
    #pragma unroll
    for (int d = 1; d < 32; d <<= 1) {
      uint32_t o = __shfl_down(suf, d, 64);
      if (lane + d < 32) suf += o;
    }
    unsigned long long m = __ballot(lane < 32 && suf >= (uint32_t)TOPK);
    int sc = 63 - __builtin_clzll(m);
    uint32_t acc0 = __shfl(suf, sc + 1, 64);

    uint32_t cs = (lane < 32) ? csum[sc * 32 + lane] : 0;
    uint32_t suf2 = cs;
    #pragma unroll
    for (int d = 1; d < 32; d <<= 1) {
      uint32_t o = __shfl_down(suf2, d, 64);
      if (lane + d < 32) suf2 += o;
    }
    m = __ballot(lane < 32 && (acc0 + suf2) >= (uint32_t)TOPK);
    int ch = 63 - __builtin_clzll(m);
    uint32_t acc1 = acc0 + __shfl(suf2, ch + 1, 64);
    int chunk = sc * 32 + ch;

    uint32_t hv = (lane < 8) ? hist[chunk * 8 + lane] : 0;
    uint32_t suf3 = hv;
    #pragma unroll
    for (int d = 1; d < 8; d <<= 1) {
      uint32_t o = __shfl_down(suf3, d, 64);
      if (lane + d < 8) suf3 += o;
    }
    m = __ballot(lane < 8 && (acc1 + suf3) >= (uint32_t)TOPK);
    int bk = 63 - __builtin_clzll(m);
    uint32_t A = acc1 + __shfl(suf3, bk + 1, 64);
    if (lane == 0) { sh_T = (uint32_t)(chunk * 8 + bk); sh_A = A; }
  }
  __syncthreads();

  const uint32_t T = sh_T;
  const uint32_t A = sh_A;
  const uint32_t C = hist[T];

  if (A + C <= FCAP) {
    for (int i = tid; i < ROW / 4; i += 1024) {
      float4 v = row4[i];
      #pragma unroll
      for (int c = 0; c < 4; ++c) {
        uint32_t bits = score_bits((&v.x)[c]);
        uint32_t bk2 = bits >> 17; bk2 = bk2 < NB ? bk2 : NB - 1;
        if (bk2 >= T) {
          uint32_t pos = atomicAdd(&sh_cnt, 1u);
          cand[pos] = ((uint64_t)bits << 32) | (uint32_t)~(uint32_t)(i * 4 + c);
        }
      }
    }
  } else {
    for (int i = tid; i < 256; i += 1024) hist2[i] = 0;
    __syncthreads();
    for (int i = tid; i < ROW / 4; i += 1024) {
      float4 v = row4[i];
      #pragma unroll
      for (int c = 0; c < 4; ++c) {
        uint32_t bits = score_bits((&v.x)[c]);
        uint32_t bk2 = bits >> 17; bk2 = bk2 < NB ? bk2 : NB - 1;
        if (bk2 == T) atomicAdd(&hist2[(bits >> 9) & 0xFF], 1u);
      }
    }
    __syncthreads();
    if (tid < 64) {
      const int lane = tid;
      uint32_t h4 = 0;
      #pragma unroll
      for (int j = 0; j < 4; ++j) h4 += hist2[lane * 4 + j];
      uint32_t suf = h4;
      #pragma unroll
      for (int d = 1; d < 64; d <<= 1) {
        uint32_t o = __shfl_down(suf, d, 64);
        if (lane + d < 64) suf += o;
      }
      unsigned long long m = __ballot((A + suf) >= (uint32_t)TOPK);
      int g = 63 - __builtin_clzll(m);
      uint32_t accg = A + ((g < 63) ? __shfl(suf, g + 1, 64) : 0u);
      uint32_t hb = (lane < 4) ? hist2[g * 4 + lane] : 0;
      uint32_t sufb = hb;
      #pragma unroll
      for (int d = 1; d < 4; d <<= 1) {
        uint32_t o = __shfl_down(sufb, d, 64);
        if (lane + d < 4) sufb += o;
      }
      m = __ballot(lane < 4 && (accg + sufb) >= (uint32_t)TOPK);
      int bin = 63 - __builtin_clzll(m);
      if (lane == 0) sh_T2 = (uint32_t)(g * 4 + bin);
    }
    __syncthreads();
    const uint32_t T2 = sh_T2;
    for (int i = tid; i < ROW / 4; i += 1024) {
      float4 v = row4[i];
      #pragma unroll
      for (int c = 0; c < 4; ++c) {
        uint32_t bits = score_bits((&v.x)[c]);
        uint32_t bk2 = bits >> 17; bk2 = bk2 < NB ? bk2 : NB - 1;
        bool take = (bk2 > T) || (bk2 == T && ((bits >> 9) & 0xFF) >= T2);
        if (take) {
          uint32_t pos = atomicAdd(&sh_cnt, 1u);
          if (pos < FCAP) cand[pos] = ((uint64_t)bits << 32) | (uint32_t)~(uint32_t)(i * 4 + c);
        }
      }
    }
  }
  __syncthreads();

  const uint32_t M = sh_cnt < FCAP ? sh_cnt : FCAP;

  float* out_labels = out;
  float4* out_boxes = (float4*)(out + BATCH * TOPK);
  float* out_scores = out + BATCH * TOPK + BATCH * TOPK * 4;
  const float4* brow = (const float4*)(boxes + (size_t)b * NQ * 4);
  const float img_h = (float)sizes[2 * b];
  const float img_w = (float)sizes[2 * b + 1];

  for (int i = tid; i < (int)M; i += 1024) {
    uint64_t key = cand[i];
    int rank = 0;
    for (uint32_t mi = 0; mi < M; ++mi) rank += (cand[mi] > key) ? 1 : 0;
    if (rank < TOPK) {
      uint32_t bits = (uint32_t)(key >> 32);
      uint32_t idx = ~(uint32_t)(key & 0xFFFFFFFFull);
      int q = (int)(idx / NCLS);
      int cls = (int)idx - q * NCLS;
      float4 pb = brow[q];
      float x0 = (pb.x - 0.5f * pb.z) * img_w;
      float y0 = (pb.y - 0.5f * pb.w) * img_h;
      float w2 = pb.z * img_w;
      float h2 = pb.w * img_h;
      x0 = fmaxf(x0, 0.f); y0 = fmaxf(y0, 0.f);
      w2 = fmaxf(w2, 1.f); h2 = fmaxf(h2, 1.f);
      int o = b * TOPK + rank;
      out_labels[o] = (float)cls;
      out_boxes[o] = make_float4(x0, y0, w2, h2);
      out_scores[o] = __uint_as_float(bits);
    }
  }
}

extern "C" void kernel_launch(void* const* d_in, const int* in_sizes, int n_in,
                              void* d_out, int out_size, void* d_ws, size_t ws_size,
                              hipStream_t stream) {
  const float* logits = (const float*)d_in[0];
  const float* boxes  = (const float*)d_in[1];
  const int*   sizes  = (const int*)d_in[2];
  float*       outp   = (float*)d_out;
  (void)in_sizes; (void)n_in; (void)out_size; (void)ws_size;

  char* ws = (char*)d_ws;
  uint64_t* cand_g = (uint64_t*)(ws + WS_CAND);
  uint32_t* cnt_g  = (uint32_t*)(ws + WS_CNT);
  uint32_t* flag_g = (uint32_t*)(ws + WS_FLAG);

  // zero cnt + flag (contiguous)
  hipMemsetAsync(ws + WS_CNT, 0, BATCH * 32 * 4 + BATCH * 4, stream);

  k1_collect<<<BATCH * SPLIT, 256, 0, stream>>>(logits, cand_g, cnt_g);
  k2_rank<<<BATCH, 1024, 0, stream>>>(cand_g, cnt_g, flag_g, boxes, sizes, outp);
  k3_fallback<<<BATCH, 1024, 0, stream>>>(flag_g, logits, boxes, sizes, outp);
}

// Round 4
// 45.492 us; speedup vs baseline: 4.8520x; 1.1191x over previous
//
#include <hip/hip_runtime.h>
#include <stdint.h>

// RT-DETR post-processing, round 4.
// R3 lesson: the in-graph hipMemsetAsync (17 KB!) cost 48us/replay — 94% of
// total. This version needs NO pre-zeroed state:
//   k1: per-(row,part) blocks count candidates (logit > 2.6) into private
//       segments, plain-store their count (no init, no cross-block atomics).
//   k2: prefix-sum 16 part counts, compact to LDS, exact O(M^2) rank + emit.
//       Writes flag[b] (0/1) unconditionally.
//   k3: exact per-row fallback (R1's proven kernel) if the gate failed.
// Selection semantics (proven R1-R3): top-300 by (sigmoid_bits<<32)|~idx.

#define BATCH 128
#define NCLS 80
#define NQ 2000
#define ROW (NQ * NCLS)     // 160000
#define TOPK 300
#define SPLIT 16
#define CHUNK (ROW / SPLIT) // 10000
#define SEGCAP 128          // per-part candidate cap (mean ~47, +12 sigma)
#define CAP (SPLIT * SEGCAP) // 2048 total per row
#define LOGIT_T 2.6f

// ws layout (bytes), nothing pre-zeroed:
//   cand : [BATCH][SPLIT][SEGCAP] u64 @ 0       (2 MB)
//   cnt  : [BATCH][SPLIT] u32        @ WS_CNT   (8 KB)
//   flag : [BATCH] u32               @ WS_FLAG  (512 B)
#define WS_CAND 0
#define WS_CNT  (BATCH * SPLIT * SEGCAP * 8)
#define WS_FLAG (WS_CNT + BATCH * SPLIT * 4)

__device__ __forceinline__ uint32_t score_bits(float x) {
  float e = expf(-fabsf(x));
  float num = (x >= 0.f) ? 1.f : e;
  float s = num / (1.f + e);
  return __float_as_uint(s);
}

// ---- k1: gate on raw logit, write private segment + count ----
__global__ __launch_bounds__(256)
void k1_collect(const float* __restrict__ logits,
                uint64_t* __restrict__ cand_g,
                uint32_t* __restrict__ cnt_g)
{
  __shared__ uint32_t lcnt;
  const int row = blockIdx.x >> 4;          // SPLIT=16
  const int part = blockIdx.x & 15;
  const int tid = threadIdx.x;
  if (tid == 0) lcnt = 0;
  __syncthreads();

  const float4* p = (const float4*)(logits + (size_t)row * ROW + part * CHUNK);
  uint64_t* seg = cand_g + ((size_t)row * SPLIT + part) * SEGCAP;

  for (int i = tid; i < CHUNK / 4; i += 256) {
    float4 v = p[i];
    #pragma unroll
    for (int c = 0; c < 4; ++c) {
      float x = (&v.x)[c];
      if (x > LOGIT_T) {
        uint32_t bits = score_bits(x);
        uint32_t idx = (uint32_t)(part * CHUNK + i * 4 + c);
        uint32_t pos = atomicAdd(&lcnt, 1u);
        if (pos < SEGCAP) seg[pos] = ((uint64_t)bits << 32) | (uint32_t)~idx;
      }
    }
  }
  __syncthreads();
  if (tid == 0) cnt_g[row * SPLIT + part] = lcnt;  // plain store, no init needed
}

// ---- k2: compact segments, exact rank, emit; set flag on gate failure ----
__global__ __launch_bounds__(1024)
void k2_rank(const uint64_t* __restrict__ cand_g,
             const uint32_t* __restrict__ cnt_g,
             uint32_t* __restrict__ flag_g,
             const float* __restrict__ boxes,
             const int* __restrict__ sizes,
             float* __restrict__ out)
{
  __shared__ uint64_t cand[CAP];        // 16 KB
  __shared__ uint32_t pc[SPLIT], pfx[SPLIT + 1];
  __shared__ uint32_t sh_bad;
  const int b = blockIdx.x;
  const int tid = threadIdx.x;

  if (tid == 0) {
    uint32_t total = 0, bad = 0;
    #pragma unroll
    for (int p = 0; p < SPLIT; ++p) {
      uint32_t c = cnt_g[b * SPLIT + p];
      if (c > SEGCAP) bad = 1;
      pc[p] = c;
      pfx[p] = total;
      total += c;
    }
    pfx[SPLIT] = total;
    if (total < TOPK) bad = 1;
    sh_bad = bad;
    flag_g[b] = bad;                    // unconditional write, no init needed
  }
  __syncthreads();
  if (sh_bad) return;

  const uint32_t M = pfx[SPLIT];
  const uint64_t* crow = cand_g + (size_t)b * SPLIT * SEGCAP;
  #pragma unroll
  for (int p = 0; p < SPLIT; ++p) {
    for (int j = tid; j < (int)pc[p]; j += 1024)
      cand[pfx[p] + j] = crow[p * SEGCAP + j];
  }
  __syncthreads();

  float* out_labels = out;
  float4* out_boxes = (float4*)(out + BATCH * TOPK);
  float* out_scores = out + BATCH * TOPK + BATCH * TOPK * 4;
  const float4* brow = (const float4*)(boxes + (size_t)b * NQ * 4);
  const float img_h = (float)sizes[2 * b];
  const float img_w = (float)sizes[2 * b + 1];

  for (int i = tid; i < (int)M; i += 1024) {
    uint64_t key = cand[i];
    int rank = 0;
    for (uint32_t mi = 0; mi < M; ++mi) rank += (cand[mi] > key) ? 1 : 0;
    if (rank < TOPK) {
      uint32_t bits = (uint32_t)(key >> 32);
      uint32_t idx = ~(uint32_t)(key & 0xFFFFFFFFull);
      int q = (int)(idx / NCLS);
      int cls = (int)idx - q * NCLS;
      float4 pb = brow[q];
      float x0 = (pb.x - 0.5f * pb.z) * img_w;
      float y0 = (pb.y - 0.5f * pb.w) * img_h;
      float w2 = pb.z * img_w;
      float h2 = pb.w * img_h;
      x0 = fmaxf(x0, 0.f); y0 = fmaxf(y0, 0.f);
      w2 = fmaxf(w2, 1.f); h2 = fmaxf(h2, 1.f);
      int o = b * TOPK + rank;
      out_labels[o] = (float)cls;
      out_boxes[o] = make_float4(x0, y0, w2, h2);
      out_scores[o] = __uint_as_float(bits);
    }
  }
}

// ---- k3: exact per-row fallback (proven R1 algorithm), only if flagged ----
#define NB 8192
#define FCAP 2048

__global__ __launch_bounds__(1024, 1)
void k3_fallback(const uint32_t* __restrict__ flag_g,
                 const float* __restrict__ logits,
                 const float* __restrict__ boxes,
                 const int* __restrict__ sizes,
                 float* __restrict__ out)
{
  const int b = blockIdx.x;
  if (!flag_g[b]) return;   // uniform across block, before any barrier

  __shared__ uint32_t hist[NB];
  __shared__ uint64_t cand[FCAP];
  __shared__ uint32_t csum[1024];
  __shared__ uint32_t hist2[256];
  __shared__ uint32_t sh_T, sh_A, sh_T2, sh_cnt;

  const int tid = threadIdx.x;
  const float4* row4 = (const float4*)(logits + (size_t)b * ROW);

  for (int i = tid; i < NB; i += 1024) hist[i] = 0;
  if (tid == 0) sh_cnt = 0;
  __syncthreads();

  for (int i = tid; i < ROW / 4; i += 1024) {
    float4 v = row4[i];
    #pragma unroll
    for (int c = 0; c < 4; ++c) {
      uint32_t bk = score_bits((&v.x)[c]) >> 17;
      bk = bk < NB ? bk : NB - 1;
      atomicAdd(&hist[bk], 1u);
    }
  }
  __syncthreads();

  {
    uint32_t s = 0;
    #pragma unroll
    for (int j = 0; j < NB / 1024; ++j) s += hist[tid * (NB / 1024) + j];
    csum[tid] = s;
  }
  __syncthreads();

  if (tid < 64) {
    const int lane = tid;
    uint32_t ss = 0;
    if (lane < 32) {
      #pragma unroll
      for (int j = 0; j < 32; ++j) ss += csum[lane * 32 + j];
    }
    uint32_t suf = ss;
    #pragma unroll
    for (int d = 1; d < 32; d <<= 1) {
      uint32_t o = __shfl_down(suf, d, 64);
      if (lane + d < 32) suf += o;
    }
    unsigned long long m = __ballot(lane < 32 && suf >= (uint32_t)TOPK);
    int sc = 63 - __builtin_clzll(m);
    uint32_t acc0 = __shfl(suf, sc + 1, 64);

    uint32_t cs = (lane < 32) ? csum[sc * 32 + lane] : 0;
    uint32_t suf2 = cs;
    #pragma unroll
    for (int d = 1; d < 32; d <<= 1) {
      uint32_t o = __shfl_down(suf2, d, 64);
      if (lane + d < 32) suf2 += o;
    }
    m = __ballot(lane < 32 && (acc0 + suf2) >= (uint32_t)TOPK);
    int ch = 63 - __builtin_clzll(m);
    uint32_t acc1 = acc0 + __shfl(suf2, ch + 1, 64);
    int chunk = sc * 32 + ch;

    uint32_t hv = (lane < 8) ? hist[chunk * 8 + lane] : 0;
    uint32_t suf3 = hv;
    #pragma unroll
    for (int d = 1; d < 8; d <<= 1) {
      uint32_t o = __shfl_down(suf3, d, 64);
      if (lane + d < 8) suf3 += o;
    }
    m = __ballot(lane < 8 && (acc1 + suf3) >= (uint32_t)TOPK);
    int bk = 63 - __builtin_clzll(m);
    uint32_t A = acc1 + __shfl(suf3, bk + 1, 64);
    if (lane == 0) { sh_T = (uint32_t)(chunk * 8 + bk); sh_A = A; }
  }
  __syncthreads();

  const uint32_t T = sh_T;
  const uint32_t A = sh_A;
  const uint32_t C = hist[T];

  if (A + C <= FCAP) {
    for (int i = tid; i < ROW / 4; i += 1024) {
      float4 v = row4[i];
      #pragma unroll
      for (int c = 0; c < 4; ++c) {
        uint32_t bits = score_bits((&v.x)[c]);
        uint32_t bk2 = bits >> 17; bk2 = bk2 < NB ? bk2 : NB - 1;
        if (bk2 >= T) {
          uint32_t pos = atomicAdd(&sh_cnt, 1u);
          cand[pos] = ((uint64_t)bits << 32) | (uint32_t)~(uint32_t)(i * 4 + c);
        }
      }
    }
  } else {
    for (int i = tid; i < 256; i += 1024) hist2[i] = 0;
    __syncthreads();
    for (int i = tid; i < ROW / 4; i += 1024) {
      float4 v = row4[i];
      #pragma unroll
      for (int c = 0; c < 4; ++c) {
        uint32_t bits = score_bits((&v.x)[c]);
        uint32_t bk2 = bits >> 17; bk2 = bk2 < NB ? bk2 : NB - 1;
        if (bk2 == T) atomicAdd(&hist2[(bits >> 9) & 0xFF], 1u);
      }
    }
    __syncthreads();
    if (tid < 64) {
      const int lane = tid;
      uint32_t h4 = 0;
      #pragma unroll
      for (int j = 0; j < 4; ++j) h4 += hist2[lane * 4 + j];
      uint32_t suf = h4;
      #pragma unroll
      for (int d = 1; d < 64; d <<= 1) {
        uint32_t o = __shfl_down(suf, d, 64);
        if (lane + d < 64) suf += o;
      }
      unsigned long long m = __ballot((A + suf) >= (uint32_t)TOPK);
      int g = 63 - __builtin_clzll(m);
      uint32_t accg = A + ((g < 63) ? __shfl(suf, g + 1, 64) : 0u);
      uint32_t hb = (lane < 4) ? hist2[g * 4 + lane] : 0;
      uint32_t sufb = hb;
      #pragma unroll
      for (int d = 1; d < 4; d <<= 1) {
        uint32_t o = __shfl_down(sufb, d, 64);
        if (lane + d < 4) sufb += o;
      }
      m = __ballot(lane < 4 && (accg + sufb) >= (uint32_t)TOPK);
      int bin = 63 - __builtin_clzll(m);
      if (lane == 0) sh_T2 = (uint32_t)(g * 4 + bin);
    }
    __syncthreads();
    const uint32_t T2 = sh_T2;
    for (int i = tid; i < ROW / 4; i += 1024) {
      float4 v = row4[i];
      #pragma unroll
      for (int c = 0; c < 4; ++c) {
        uint32_t bits = score_bits((&v.x)[c]);
        uint32_t bk2 = bits >> 17; bk2 = bk2 < NB ? bk2 : NB - 1;
        bool take = (bk2 > T) || (bk2 == T && ((bits >> 9) & 0xFF) >= T2);
        if (take) {
          uint32_t pos = atomicAdd(&sh_cnt, 1u);
          if (pos < FCAP) cand[pos] = ((uint64_t)bits << 32) | (uint32_t)~(uint32_t)(i * 4 + c);
        }
      }
    }
  }
  __syncthreads();

  const uint32_t M = sh_cnt < FCAP ? sh_cnt : FCAP;

  float* out_labels = out;
  float4* out_boxes = (float4*)(out + BATCH * TOPK);
  float* out_scores = out + BATCH * TOPK + BATCH * TOPK * 4;
  const float4* brow = (const float4*)(boxes + (size_t)b * NQ * 4);
  const float img_h = (float)sizes[2 * b];
  const float img_w = (float)sizes[2 * b + 1];

  for (int i = tid; i < (int)M; i += 1024) {
    uint64_t key = cand[i];
    int rank = 0;
    for (uint32_t mi = 0; mi < M; ++mi) rank += (cand[mi] > key) ? 1 : 0;
    if (rank < TOPK) {
      uint32_t bits = (uint32_t)(key >> 32);
      uint32_t idx = ~(uint32_t)(key & 0xFFFFFFFFull);
      int q = (int)(idx / NCLS);
      int cls = (int)idx - q * NCLS;
      float4 pb = brow[q];
      float x0 = (pb.x - 0.5f * pb.z) * img_w;
      float y0 = (pb.y - 0.5f * pb.w) * img_h;
      float w2 = pb.z * img_w;
      float h2 = pb.w * img_h;
      x0 = fmaxf(x0, 0.f); y0 = fmaxf(y0, 0.f);
      w2 = fmaxf(w2, 1.f); h2 = fmaxf(h2, 1.f);
      int o = b * TOPK + rank;
      out_labels[o] = (float)cls;
      out_boxes[o] = make_float4(x0, y0, w2, h2);
      out_scores[o] = __uint_as_float(bits);
    }
  }
}

extern "C" void kernel_launch(void* const* d_in, const int* in_sizes, int n_in,
                              void* d_out, int out_size, void* d_ws, size_t ws_size,
                              hipStream_t stream) {
  const float* logits = (const float*)d_in[0];
  const float* boxes  = (const float*)d_in[1];
  const int*   sizes  = (const int*)d_in[2];
  float*       outp   = (float*)d_out;
  (void)in_sizes; (void)n_in; (void)out_size; (void)ws_size;

  char* ws = (char*)d_ws;
  uint64_t* cand_g = (uint64_t*)(ws + WS_CAND);
  uint32_t* cnt_g  = (uint32_t*)(ws + WS_CNT);
  uint32_t* flag_g = (uint32_t*)(ws + WS_FLAG);

  k1_collect<<<BATCH * SPLIT, 256, 0, stream>>>(logits, cand_g, cnt_g);
  k2_rank<<<BATCH, 1024, 0, stream>>>(cand_g, cnt_g, flag_g, boxes, sizes, outp);
  k3_fallback<<<BATCH, 1024, 0, stream>>>(flag_g, logits, boxes, sizes, outp);
}

// Round 5
// 28.206 us; speedup vs baseline: 7.8257x; 1.6129x over previous
//
#include <hip/hip_runtime.h>
#include <stdint.h>

// RT-DETR post-processing, round 5.
// Two dispatches only:
//   k1: 2048 blocks x 256 — gate raw logit > 2.6 (monotone in sigmoid),
//       private per-(row,part) segments + plain count store (no init needed).
//   k2: 128 blocks x 1024 — parallel prefix of part counts, parallel
//       compaction, 512-bin hist cut -> exact rank among ~320 keep set,
//       box epilogue. Inline exact full-row fallback (R1's proven algo)
//       if the gate assumption fails (never on N(0,1) data).
// Selection semantics (proven R1-R4, absmax 0): top-300 by composite key
// (sigmoid_bits<<32)|~idx == (score desc, index asc) exactly.

#define BATCH 128
#define NCLS 80
#define NQ 2000
#define ROW (NQ * NCLS)     // 160000
#define TOPK 300
#define SPLIT 16
#define CHUNK (ROW / SPLIT) // 10000 floats, 1250 float4-pairs
#define SEGCAP 128
#define CAP (SPLIT * SEGCAP) // 2048
#define KEEPCAP 512
#define LOGIT_T 2.6f

// ws layout (bytes), nothing pre-zeroed:
//   cand : [BATCH][SPLIT][SEGCAP] u64 @ 0       (2 MB)
//   cnt  : [BATCH][SPLIT] u32        @ WS_CNT   (8 KB)
#define WS_CAND 0
#define WS_CNT  (BATCH * SPLIT * SEGCAP * 8)

__device__ __forceinline__ uint32_t score_bits(float x) {
  float e = expf(-fabsf(x));
  float num = (x >= 0.f) ? 1.f : e;
  float s = num / (1.f + e);
  return __float_as_uint(s);
}

__device__ __forceinline__ uint32_t bin512(uint32_t bits) {
  // monotone over sigmoid(2.6)=0.9309.. up to 1.0 (bits 0x3F6E4..-0x3F7FFFFF)
  return (bits >= 0x3F800000u) ? 511u : ((bits >> 12) & 0x1FFu);
}

// ---- k1: gate on raw logit, write private segment + count ----
__global__ __launch_bounds__(256)
void k1_collect(const float* __restrict__ logits,
                uint64_t* __restrict__ cand_g,
                uint32_t* __restrict__ cnt_g)
{
  __shared__ uint32_t lcnt;
  const int row = blockIdx.x >> 4;          // SPLIT=16
  const int part = blockIdx.x & 15;
  const int tid = threadIdx.x;
  if (tid == 0) lcnt = 0;
  __syncthreads();

  const float4* p = (const float4*)(logits + (size_t)row * ROW + part * CHUNK);
  uint64_t* seg = cand_g + ((size_t)row * SPLIT + part) * SEGCAP;
  const uint32_t base_idx = part * CHUNK;

  for (int pi = tid; pi < CHUNK / 8; pi += 256) {
    float4 v0 = p[pi * 2];
    float4 v1 = p[pi * 2 + 1];
    float m0 = fmaxf(fmaxf(v0.x, v0.y), fmaxf(v0.z, v0.w));
    float m1 = fmaxf(fmaxf(v1.x, v1.y), fmaxf(v1.z, v1.w));
    if (m0 > LOGIT_T) {
      #pragma unroll
      for (int c = 0; c < 4; ++c) {
        float x = (&v0.x)[c];
        if (x > LOGIT_T) {
          uint32_t pos = atomicAdd(&lcnt, 1u);
          uint32_t idx = base_idx + pi * 8 + c;
          if (pos < SEGCAP) seg[pos] = ((uint64_t)score_bits(x) << 32) | (uint32_t)~idx;
        }
      }
    }
    if (m1 > LOGIT_T) {
      #pragma unroll
      for (int c = 0; c < 4; ++c) {
        float x = (&v1.x)[c];
        if (x > LOGIT_T) {
          uint32_t pos = atomicAdd(&lcnt, 1u);
          uint32_t idx = base_idx + pi * 8 + 4 + c;
          if (pos < SEGCAP) seg[pos] = ((uint64_t)score_bits(x) << 32) | (uint32_t)~idx;
        }
      }
    }
  }
  __syncthreads();
  if (tid == 0) cnt_g[row * SPLIT + part] = lcnt;  // plain store
}

// ---- k2: prefix, compact, hist-cut exact rank, emit; inline fallback ----
#define NB 8192

__global__ __launch_bounds__(1024, 1)
void k2_rank(const uint64_t* __restrict__ cand_g,
             const uint32_t* __restrict__ cnt_g,
             const float* __restrict__ logits,
             const float* __restrict__ boxes,
             const int* __restrict__ sizes,
             float* __restrict__ out)
{
  __shared__ uint64_t cand[CAP];        // 16 KB (shared with fallback)
  __shared__ uint64_t keep[KEEPCAP];    // 4 KB
  __shared__ uint32_t hist[512];        // 2 KB
  __shared__ uint32_t pc[SPLIT], pfx[SPLIT];
  __shared__ uint32_t sh_bad, sh_M, keepcnt, sh_B;
  // fallback-only:
  __shared__ uint32_t fhist[NB];        // 32 KB
  __shared__ uint32_t fcsum[1024];      // 4 KB
  __shared__ uint32_t fhist2[256];      // 1 KB
  __shared__ uint32_t sh_T, sh_A2, sh_T2, sh_cnt;

  const int b = blockIdx.x;
  const int tid = threadIdx.x;

  float* out_labels = out;
  float4* out_boxes = (float4*)(out + BATCH * TOPK);
  float* out_scores = out + BATCH * TOPK + BATCH * TOPK * 4;
  const float4* brow = (const float4*)(boxes + (size_t)b * NQ * 4);
  const float img_h = (float)sizes[2 * b];
  const float img_w = (float)sizes[2 * b + 1];

  if (tid < 512) hist[tid] = 0;
  if (tid == 0) keepcnt = 0;

  // parallel count load + wave-0 shuffle scan
  if (tid < 64) {
    uint32_t c = (tid < SPLIT) ? cnt_g[b * SPLIT + tid] : 0;
    uint32_t incl = c;
    #pragma unroll
    for (int d = 1; d < 16; d <<= 1) {
      uint32_t o = __shfl_up(incl, d, 64);
      if (tid >= d) incl += o;
    }
    if (tid < SPLIT) { pc[tid] = c; pfx[tid] = incl - c; }
    uint32_t total = __shfl(incl, SPLIT - 1, 64);
    unsigned long long over = __ballot(tid < SPLIT && c > SEGCAP);
    if (tid == 0) {
      sh_M = total;
      sh_bad = (over != 0ull || total < TOPK) ? 1u : 0u;
    }
  }
  __syncthreads();

  if (!sh_bad) {
    const uint32_t M = sh_M;
    const uint64_t* crow = cand_g + (size_t)b * SPLIT * SEGCAP;

    // parallel compaction: thread t -> part t>>6, slot r*64+(t&63)
    {
      const int p = tid >> 6;
      const int jl = tid & 63;
      #pragma unroll
      for (int r = 0; r < SEGCAP / 64; ++r) {
        int j = r * 64 + jl;
        if (j < (int)pc[p]) cand[pfx[p] + j] = crow[p * SEGCAP + j];
      }
    }
    __syncthreads();

    // 512-bin histogram of candidate score bits
    for (int i = tid; i < (int)M; i += 1024)
      atomicAdd(&hist[bin512((uint32_t)(cand[i] >> 32))], 1u);
    __syncthreads();

    // threshold super-bin (coarse, 8-bin granularity): keep = bins >= B
    if (tid < 64) {
      const int lane = tid;
      uint32_t s = 0;
      #pragma unroll
      for (int j = 0; j < 8; ++j) s += hist[lane * 8 + j];
      uint32_t suf = s;
      #pragma unroll
      for (int d = 1; d < 64; d <<= 1) {
        uint32_t o = __shfl_down(suf, d, 64);
        if (lane + d < 64) suf += o;
      }
      unsigned long long m = __ballot(suf >= (uint32_t)TOPK);
      int L = 63 - __builtin_clzll(m);    // exists since M >= TOPK
      if (lane == 0) sh_B = (uint32_t)(L * 8);
    }
    __syncthreads();

    // compact keep set (superset of top-300)
    const uint32_t Bbin = sh_B;
    for (int i = tid; i < (int)M; i += 1024) {
      uint64_t key = cand[i];
      if (bin512((uint32_t)(key >> 32)) >= Bbin) {
        uint32_t pos = atomicAdd(&keepcnt, 1u);
        if (pos < KEEPCAP) keep[pos] = key;
      }
    }
    __syncthreads();
    const uint32_t KN = keepcnt;

    if (KN <= KEEPCAP) {
      for (int i = tid; i < (int)KN; i += 1024) {
        uint64_t key = keep[i];
        int rank = 0;
        for (uint32_t j = 0; j < KN; ++j) rank += (keep[j] > key) ? 1 : 0;
        if (rank < TOPK) {
          uint32_t bits = (uint32_t)(key >> 32);
          uint32_t idx = ~(uint32_t)(key & 0xFFFFFFFFull);
          int q = (int)(idx / NCLS);
          int cls = (int)idx - q * NCLS;
          float4 pb = brow[q];
          float x0 = fmaxf((pb.x - 0.5f * pb.z) * img_w, 0.f);
          float y0 = fmaxf((pb.y - 0.5f * pb.w) * img_h, 0.f);
          float w2 = fmaxf(pb.z * img_w, 1.f);
          float h2 = fmaxf(pb.w * img_h, 1.f);
          int o = b * TOPK + rank;
          out_labels[o] = (float)cls;
          out_boxes[o] = make_float4(x0, y0, w2, h2);
          out_scores[o] = __uint_as_float(bits);
        }
      }
    } else {
      // keep overflow (pathological distribution): exact O(M^2) on cand
      for (int i = tid; i < (int)M; i += 1024) {
        uint64_t key = cand[i];
        int rank = 0;
        for (uint32_t j = 0; j < M; ++j) rank += (cand[j] > key) ? 1 : 0;
        if (rank < TOPK) {
          uint32_t bits = (uint32_t)(key >> 32);
          uint32_t idx = ~(uint32_t)(key & 0xFFFFFFFFull);
          int q = (int)(idx / NCLS);
          int cls = (int)idx - q * NCLS;
          float4 pb = brow[q];
          float x0 = fmaxf((pb.x - 0.5f * pb.z) * img_w, 0.f);
          float y0 = fmaxf((pb.y - 0.5f * pb.w) * img_h, 0.f);
          float w2 = fmaxf(pb.z * img_w, 1.f);
          float h2 = fmaxf(pb.w * img_h, 1.f);
          int o = b * TOPK + rank;
          out_labels[o] = (float)cls;
          out_boxes[o] = make_float4(x0, y0, w2, h2);
          out_scores[o] = __uint_as_float(bits);
        }
      }
    }
    return;
  }

  // ======== inline exact full-row fallback (R1's proven algorithm) ========
  const float4* row4 = (const float4*)(logits + (size_t)b * ROW);

  for (int i = tid; i < NB; i += 1024) fhist[i] = 0;
  if (tid == 0) sh_cnt = 0;
  __syncthreads();

  for (int i = tid; i < ROW / 4; i += 1024) {
    float4 v = row4[i];
    #pragma unroll
    for (int c = 0; c < 4; ++c) {
      uint32_t bk = score_bits((&v.x)[c]) >> 17;
      bk = bk < NB ? bk : NB - 1;
      atomicAdd(&fhist[bk], 1u);
    }
  }
  __syncthreads();

  {
    uint32_t s = 0;
    #pragma unroll
    for (int j = 0; j < NB / 1024; ++j) s += fhist[tid * (NB / 1024) + j];
    fcsum[tid] = s;
  }
  __syncthreads();

  if (tid < 64) {
    const int lane = tid;
    uint32_t ss = 0;
    if (lane < 32) {
      #pragma unroll
      for (int j = 0; j < 32; ++j) ss += fcsum[lane * 32 + j];
    }
    uint32_t suf = ss;
    #pragma unroll
    for (int d = 1; d < 32; d <<= 1) {
      uint32_t o = __shfl_down(suf, d, 64);
      if (lane + d < 32) suf += o;
    }
    unsigned long long m = __ballot(lane < 32 && suf >= (uint32_t)TOPK);
    int sc = 63 - __builtin_clzll(m);
    uint32_t acc0 = __shfl(suf, sc + 1, 64);

    uint32_t cs = (lane < 32) ? fcsum[sc * 32 + lane] : 0;
    uint32_t suf2 = cs;
    #pragma unroll
    for (int d = 1; d < 32; d <<= 1) {
      uint32_t o = __shfl_down(suf2, d, 64);
      if (lane + d < 32) suf2 += o;
    }
    m = __ballot(lane < 32 && (acc0 + suf2) >= (uint32_t)TOPK);
    int ch = 63 - __builtin_clzll(m);
    uint32_t acc1 = acc0 + __shfl(suf2, ch + 1, 64);
    int chunk = sc * 32 + ch;

    uint32_t hv = (lane < 8) ? fhist[chunk * 8 + lane] : 0;
    uint32_t suf3 = hv;
    #pragma unroll
    for (int d = 1; d < 8; d <<= 1) {
      uint32_t o = __shfl_down(suf3, d, 64);
      if (lane + d < 8) suf3 += o;
    }
    m = __ballot(lane < 8 && (acc1 + suf3) >= (uint32_t)TOPK);
    int bk = 63 - __builtin_clzll(m);
    uint32_t A = acc1 + __shfl(suf3, bk + 1, 64);
    if (lane == 0) { sh_T = (uint32_t)(chunk * 8 + bk); sh_A2 = A; }
  }
  __syncthreads();

  const uint32_t T = sh_T;
  const uint32_t A = sh_A2;
  const uint32_t C = fhist[T];

  if (A + C <= CAP) {
    for (int i = tid; i < ROW / 4; i += 1024) {
      float4 v = row4[i];
      #pragma unroll
      for (int c = 0; c < 4; ++c) {
        uint32_t bits = score_bits((&v.x)[c]);
        uint32_t bk2 = bits >> 17; bk2 = bk2 < NB ? bk2 : NB - 1;
        if (bk2 >= T) {
          uint32_t pos = atomicAdd(&sh_cnt, 1u);
          cand[pos] = ((uint64_t)bits << 32) | (uint32_t)~(uint32_t)(i * 4 + c);
        }
      }
    }
  } else {
    for (int i = tid; i < 256; i += 1024) fhist2[i] = 0;
    __syncthreads();
    for (int i = tid; i < ROW / 4; i += 1024) {
      float4 v = row4[i];
      #pragma unroll
      for (int c = 0; c < 4; ++c) {
        uint32_t bits = score_bits((&v.x)[c]);
        uint32_t bk2 = bits >> 17; bk2 = bk2 < NB ? bk2 : NB - 1;
        if (bk2 == T) atomicAdd(&fhist2[(bits >> 9) & 0xFF], 1u);
      }
    }
    __syncthreads();
    if (tid < 64) {
      const int lane = tid;
      uint32_t h4 = 0;
      #pragma unroll
      for (int j = 0; j < 4; ++j) h4 += fhist2[lane * 4 + j];
      uint32_t suf = h4;
      #pragma unroll
      for (int d = 1; d < 64; d <<= 1) {
        uint32_t o = __shfl_down(suf, d, 64);
        if (lane + d < 64) suf += o;
      }
      unsigned long long m = __ballot((A + suf) >= (uint32_t)TOPK);
      int g = 63 - __builtin_clzll(m);
      uint32_t accg = A + ((g < 63) ? __shfl(suf, g + 1, 64) : 0u);
      uint32_t hb = (lane < 4) ? fhist2[g * 4 + lane] : 0;
      uint32_t sufb = hb;
      #pragma unroll
      for (int d = 1; d < 4; d <<= 1) {
        uint32_t o = __shfl_down(sufb, d, 64);
        if (lane + d < 4) sufb += o;
      }
      m = __ballot(lane < 4 && (accg + sufb) >= (uint32_t)TOPK);
      int bin = 63 - __builtin_clzll(m);
      if (lane == 0) sh_T2 = (uint32_t)(g * 4 + bin);
    }
    __syncthreads();
    const uint32_t T2 = sh_T2;
    for (int i = tid; i < ROW / 4; i += 1024) {
      float4 v = row4[i];
      #pragma unroll
      for (int c = 0; c < 4; ++c) {
        uint32_t bits = score_bits((&v.x)[c]);
        uint32_t bk2 = bits >> 17; bk2 = bk2 < NB ? bk2 : NB - 1;
        bool take = (bk2 > T) || (bk2 == T && ((bits >> 9) & 0xFF) >= T2);
        if (take) {
          uint32_t pos = atomicAdd(&sh_cnt, 1u);
          if (pos < CAP) cand[pos] = ((uint64_t)bits << 32) | (uint32_t)~(uint32_t)(i * 4 + c);
        }
      }
    }
  }
  __syncthreads();

  const uint32_t M = sh_cnt < CAP ? sh_cnt : CAP;
  for (int i = tid; i < (int)M; i += 1024) {
    uint64_t key = cand[i];
    int rank = 0;
    for (uint32_t mi = 0; mi < M; ++mi) rank += (cand[mi] > key) ? 1 : 0;
    if (rank < TOPK) {
      uint32_t bits = (uint32_t)(key >> 32);
      uint32_t idx = ~(uint32_t)(key & 0xFFFFFFFFull);
      int q = (int)(idx / NCLS);
      int cls = (int)idx - q * NCLS;
      float4 pb = brow[q];
      float x0 = fmaxf((pb.x - 0.5f * pb.z) * img_w, 0.f);
      float y0 = fmaxf((pb.y - 0.5f * pb.w) * img_h, 0.f);
      float w2 = fmaxf(pb.z * img_w, 1.f);
      float h2 = fmaxf(pb.w * img_h, 1.f);
      int o = b * TOPK + rank;
      out_labels[o] = (float)cls;
      out_boxes[o] = make_float4(x0, y0, w2, h2);
      out_scores[o] = __uint_as_float(bits);
    }
  }
}

extern "C" void kernel_launch(void* const* d_in, const int* in_sizes, int n_in,
                              void* d_out, int out_size, void* d_ws, size_t ws_size,
                              hipStream_t stream) {
  const float* logits = (const float*)d_in[0];
  const float* boxes  = (const float*)d_in[1];
  const int*   sizes  = (const int*)d_in[2];
  float*       outp   = (float*)d_out;
  (void)in_sizes; (void)n_in; (void)out_size; (void)ws_size;

  char* ws = (char*)d_ws;
  uint64_t* cand_g = (uint64_t*)(ws + WS_CAND);
  uint32_t* cnt_g  = (uint32_t*)(ws + WS_CNT);

  k1_collect<<<BATCH * SPLIT, 256, 0, stream>>>(logits, cand_g, cnt_g);
  k2_rank<<<BATCH, 1024, 0, stream>>>(cand_g, cnt_g, logits, boxes, sizes, outp);
}